// Round 3
// baseline (217.587 us; speedup 1.0000x reference)
//
#include <hip/hip_runtime.h>
#include <hip/hip_bf16.h>
#include <stdint.h>

namespace {
constexpr int kBatch = 256;
constexpr int kNoise = 128;
constexpr int kIn    = 512;
constexpr int kOut   = 512;
constexpr int kXCols = kNoise + kIn;        // 640
constexpr int kPCols = kIn * kOut + kOut;   // 262656 (W row stride)
constexpr int kOTile = 32;
constexpr int kITile = 16;
constexpr int kSplits = kIn / kITile;       // 32 partial slabs
constexpr int kWStride = 68;                // LDS col stride in dwords (64 kp + 4 pad)
constexpr int kFeatsStride = 260;
}

typedef __bf16 bf16x8 __attribute__((ext_vector_type(8)));
typedef float  f32x4  __attribute__((ext_vector_type(4)));
typedef unsigned int u32x4 __attribute__((ext_vector_type(4)));

__device__ inline unsigned int pack_bf16x2(float lo, float hi) {
    unsigned int a = (unsigned int)__builtin_bit_cast(unsigned short, (__bf16)lo);
    unsigned int b = (unsigned int)__builtin_bit_cast(unsigned short, (__bf16)hi);
    return a | (b << 16);
}

// Barrier draining LDS ops only (lgkmcnt(0)); vmcnt untouched so global
// prefetch loads stay in flight across it.
__device__ inline void wg_barrier_lds() {
    __asm__ volatile("" ::: "memory");
    __builtin_amdgcn_s_waitcnt(0xC07F);   // lgkmcnt(0), vmcnt/expcnt = no-wait
    __builtin_amdgcn_s_barrier();
    __asm__ volatile("" ::: "memory");
}

// Stage 1: part[split][b][o] = sum_{i in split} feats[b,i]*(noise@W + bvec)[b, i*512+o]
//          (+ the bias-term pass folded into split 0)
// Grid (16 o-tiles, 32 i-splits) = 512 WGs x 512 thr (8 waves, 2 WGs/CU).
// W element -> exactly one WG (1x HBM traffic). No atomics: partials to d_ws.
__global__ __launch_bounds__(512, 4)
void hyper_gemm_kernel(const float* __restrict__ x,
                       const float* __restrict__ W,
                       const float* __restrict__ bvec,
                       float* __restrict__ part)
{
    const int tid  = threadIdx.x;
    const int lane = tid & 63;
    const int wave = tid >> 6;     // 0..7, owns batch rows [wave*32, wave*32+32)
    const int q    = lane >> 4;
    const int l16  = lane & 15;

    const int o0 = blockIdx.x * kOTile;
    const int i0 = blockIdx.y * kITile;

    // W staging role: thread covers rows {2u, 2u+1}, cols colg..colg+3
    const int u    = tid >> 3;          // 0..63 (kp index)
    const int colg = (tid & 7) * 4;

    __shared__ unsigned int wtile[2][kOTile * kWStride];   // double-buffered bf16-pair tile [col][kp]
    __shared__ float feats_lds[kITile * kFeatsStride];     // [i][b] transposed
    __shared__ float bv_lds[(kITile + 1) * kOTile];        // [pass][col]

    const int nPass = (blockIdx.y == 0) ? (kITile + 1) : kITile;

    auto pass_cbase = [&](int p) -> size_t {
        return (p == kITile) ? (size_t)(kIn * kOut) : (size_t)(i0 + p) * kOut;
    };
    auto wrow = [&](int p) -> const float* {
        return W + (size_t)(2 * u) * kPCols + pass_cbase(p) + o0 + colg;
    };

    // ---- prologue: issue depth-2 W prefetch FIRST ----
    f32x4 pa0, pa1, pb0, pb1;
    { const float* wp = wrow(0); pa0 = *(const f32x4*)wp; pa1 = *(const f32x4*)(wp + kPCols); }
    { const float* wp = wrow(1); pb0 = *(const f32x4*)wp; pb1 = *(const f32x4*)(wp + kPCols); }

    // bvec -> LDS (keeps per-pass global loads out of the vm queue)
    for (int idx = tid; idx < (kITile + 1) * kOTile; idx += 512) {
        const int p = idx >> 5, c = idx & 31;
        const size_t cb = (p == kITile) ? (size_t)(kIn * kOut) : (size_t)(i0 + p) * kOut;
        bv_lds[idx] = bvec[cb + o0 + c];
    }

    // feats[b][i0+i] -> feats_lds[i][b]
    {
        const int i    = tid & 15;
        const int brow = tid >> 4;      // 0..31
        #pragma unroll
        for (int rep = 0; rep < 8; ++rep) {
            const int b = brow + rep * 32;
            feats_lds[i * kFeatsStride + b] = x[b * kXCols + kNoise + i0 + i];
        }
    }

    // Noise A-fragments (resident). A[m=lane&15][k=q*8+j], k_global = 32*s + k.
    bf16x8 afrag[2][4];
    {
        #pragma unroll
        for (int mt = 0; mt < 2; ++mt) {
            const float* xr = x + (size_t)(wave * 32 + mt * 16 + l16) * kXCols;
            #pragma unroll
            for (int s = 0; s < 4; ++s) {
                const float* p = xr + s * 32 + q * 8;
                f32x4 u0 = *(const f32x4*)(p);
                f32x4 u1 = *(const f32x4*)(p + 4);
                bf16x8 a;
                a[0] = (__bf16)u0[0]; a[1] = (__bf16)u0[1];
                a[2] = (__bf16)u0[2]; a[3] = (__bf16)u0[3];
                a[4] = (__bf16)u1[0]; a[5] = (__bf16)u1[1];
                a[6] = (__bf16)u1[2]; a[7] = (__bf16)u1[3];
                afrag[mt][s] = a;
            }
        }
    }

    float oacc[2][2][4];   // [mt][nt][r]; b = wave*32+mt*16+q*4+r, o = o0+nt*16+l16
    #pragma unroll
    for (int mt = 0; mt < 2; ++mt)
        #pragma unroll
        for (int nt = 0; nt < 2; ++nt)
            #pragma unroll
            for (int r = 0; r < 4; ++r) oacc[mt][nt][r] = 0.f;

    __syncthreads();   // feats + bvec staged

    // ---- pipelined i-loop: 1 barrier/pass, vmcnt(2) steady state ----
    for (int ip = 0; ip < nPass; ++ip) {
        // pack pass-ip regs (waits only the 2 oldest loads -> vmcnt(2))
        unsigned int pk[4];
        #pragma unroll
        for (int cc = 0; cc < 4; ++cc) pk[cc] = pack_bf16x2(pa0[cc], pa1[cc]);

        unsigned int* wt = &wtile[ip & 1][0];
        #pragma unroll
        for (int cc = 0; cc < 4; ++cc)
            wt[(colg + cc) * kWStride + u] = pk[cc];

        pa0 = pb0; pa1 = pb1;
        if (ip + 2 < nPass) {
            const float* wp = wrow(ip + 2);
            pb0 = *(const f32x4*)wp; pb1 = *(const f32x4*)(wp + kPCols);
        }

        wg_barrier_lds();   // tile[ip&1] visible; prior-buffer readers done (via last iter's barrier)

        // GEMM: acc[b,col] = noise @ W[:, cbase+o0+col]
        f32x4 acc[2][2];
        const f32x4 zero = {0.f, 0.f, 0.f, 0.f};
        #pragma unroll
        for (int mt = 0; mt < 2; ++mt)
            #pragma unroll
            for (int nt = 0; nt < 2; ++nt) acc[mt][nt] = zero;

        #pragma unroll
        for (int s = 0; s < 4; ++s) {
            #pragma unroll
            for (int nt = 0; nt < 2; ++nt) {
                u32x4 raw = *(const u32x4*)&wt[(nt * 16 + l16) * kWStride + s * 16 + q * 4];
                bf16x8 bfrag = __builtin_bit_cast(bf16x8, raw);
                #pragma unroll
                for (int mt = 0; mt < 2; ++mt)
                    acc[mt][nt] = __builtin_amdgcn_mfma_f32_16x16x32_bf16(
                        afrag[mt][s], bfrag, acc[mt][nt], 0, 0, 0);
            }
        }

        // epilogue (fp32): oacc += feats[b,i] * (acc + bvec[c]); extra pass scale=1
        const float bv0 = bv_lds[ip * kOTile + l16];
        const float bv1 = bv_lds[ip * kOTile + 16 + l16];

        if (ip < kITile) {
            #pragma unroll
            for (int mt = 0; mt < 2; ++mt) {
                const f32x4 f4 = *(const f32x4*)&feats_lds[ip * kFeatsStride
                                        + wave * 32 + mt * 16 + q * 4];
                #pragma unroll
                for (int r = 0; r < 4; ++r) {
                    oacc[mt][0][r] += f4[r] * (acc[mt][0][r] + bv0);
                    oacc[mt][1][r] += f4[r] * (acc[mt][1][r] + bv1);
                }
            }
        } else {
            #pragma unroll
            for (int mt = 0; mt < 2; ++mt)
                #pragma unroll
                for (int r = 0; r < 4; ++r) {
                    oacc[mt][0][r] += acc[mt][0][r] + bv0;
                    oacc[mt][1][r] += acc[mt][1][r] + bv1;
                }
        }
    }

    // ---- stream partials (no atomics) ----
    float* pp = part + (size_t)blockIdx.y * kBatch * kOut;
    #pragma unroll
    for (int mt = 0; mt < 2; ++mt)
        #pragma unroll
        for (int nt = 0; nt < 2; ++nt) {
            const int o = o0 + nt * 16 + l16;
            #pragma unroll
            for (int r = 0; r < 4; ++r) {
                const int b = wave * 32 + mt * 16 + q * 4 + r;
                pp[(size_t)b * kOut + o] = oacc[mt][nt][r];
            }
        }
}

// Stage 2: out = sum over 32 slabs (16.8 MB, L3-resident -> fast)
__global__ __launch_bounds__(256)
void reduce_kernel(const float* __restrict__ part, float* __restrict__ out)
{
    const size_t idx4 = ((size_t)blockIdx.x * 256 + threadIdx.x) * 4;
    f32x4 acc = *(const f32x4*)(part + idx4);
    #pragma unroll
    for (int s = 1; s < kSplits; ++s)
        acc += *(const f32x4*)(part + (size_t)s * kBatch * kOut + idx4);
    *(f32x4*)(out + idx4) = acc;
}

extern "C" void kernel_launch(void* const* d_in, const int* in_sizes, int n_in,
                              void* d_out, int out_size, void* d_ws, size_t ws_size,
                              hipStream_t stream) {
    const float* x  = (const float*)d_in[0];
    const float* W  = (const float*)d_in[1];
    const float* bv = (const float*)d_in[2];
    float* out  = (float*)d_out;
    float* part = (float*)d_ws;   // 32 * 256 * 512 * 4 B = 16.8 MB

    dim3 grid(kOut / kOTile, kSplits);  // (16, 32) = 512 WGs of 512 threads
    hyper_gemm_kernel<<<grid, 512, 0, stream>>>(x, W, bv, part);

    const int n4 = kBatch * kOut / 4;   // 32768 f32x4 outputs
    reduce_kernel<<<n4 / 256, 256, 0, stream>>>(part, out);
}

// Round 4
// 215.466 us; speedup vs baseline: 1.0098x; 1.0098x over previous
//
#include <hip/hip_runtime.h>
#include <hip/hip_bf16.h>
#include <stdint.h>

namespace {
constexpr int kBatch = 256;
constexpr int kNoise = 128;
constexpr int kIn    = 512;
constexpr int kOut   = 512;
constexpr int kXCols = kNoise + kIn;        // 640
constexpr int kPCols = kIn * kOut + kOut;   // 262656 (W row stride)
constexpr int kOTile = 32;
constexpr int kITile = 16;
constexpr int kSplits = kIn / kITile;       // 32 partial slabs
constexpr int kWStride = 68;                // LDS col stride in dwords (64 kp + 4 pad)
constexpr int kFeatsStride = 260;
}

typedef __bf16 bf16x8 __attribute__((ext_vector_type(8)));
typedef float  f32x2  __attribute__((ext_vector_type(2)));
typedef float  f32x4  __attribute__((ext_vector_type(4)));
typedef unsigned int u32x4 __attribute__((ext_vector_type(4)));

__device__ inline unsigned int pack_bf16x2(float lo, float hi) {
    unsigned int a = (unsigned int)__builtin_bit_cast(unsigned short, (__bf16)lo);
    unsigned int b = (unsigned int)__builtin_bit_cast(unsigned short, (__bf16)hi);
    return a | (b << 16);
}

// Barrier draining LDS ops only (lgkmcnt(0)); vmcnt untouched so global
// prefetch loads stay in flight across it.
__device__ inline void wg_barrier_lds() {
    __asm__ volatile("" ::: "memory");
    __builtin_amdgcn_s_waitcnt(0xC07F);   // lgkmcnt(0), vmcnt/expcnt = no-wait
    __builtin_amdgcn_s_barrier();
    __asm__ volatile("" ::: "memory");
}

// Stage 1: part[split][b][o] = sum_{i in split} feats[b,i]*(noise@W + bvec)[b, i*512+o]
//          (+ bias-term pass folded into split 0)
// Grid (16 o-tiles, 32 i-splits) = 512 WGs x 1024 thr (16 waves).
// 2 WGs/CU = 32 waves/CU = 100% occupancy (forced <=64 VGPR via launch_bounds).
// W element -> exactly one WG (1x HBM traffic). Partials to d_ws, no atomics.
__global__ __launch_bounds__(1024, 8)
void hyper_gemm_kernel(const float* __restrict__ x,
                       const float* __restrict__ W,
                       const float* __restrict__ bvec,
                       float* __restrict__ part)
{
    const int tid  = threadIdx.x;
    const int lane = tid & 63;
    const int wave = tid >> 6;     // 0..15, owns batch rows [wave*16, wave*16+16)
    const int q    = lane >> 4;
    const int l16  = lane & 15;

    const int o0 = blockIdx.x * kOTile;
    const int i0 = blockIdx.y * kITile;

    // W staging role: thread covers rows {2u, 2u+1}, cols {c2, c2+1}
    const int u  = tid >> 4;            // 0..63 (kp index)
    const int c2 = (tid & 15) * 2;      // 0,2,..,30

    __shared__ unsigned int wtile[2][kOTile * kWStride];   // dbuf bf16-pair tile [col][kp]
    __shared__ float feats_lds[kITile * kFeatsStride];     // [i][b] transposed
    __shared__ float bv_lds[(kITile + 1) * kOTile];        // [pass][col]

    const int nPass = (blockIdx.y == 0) ? (kITile + 1) : kITile;

    auto pass_cbase = [&](int p) -> size_t {
        return (p == kITile) ? (size_t)(kIn * kOut) : (size_t)(i0 + p) * kOut;
    };
    auto wrow = [&](int p) -> const float* {
        return W + (size_t)(2 * u) * kPCols + pass_cbase(p) + o0 + c2;
    };

    // ---- prologue: issue depth-2 W prefetch FIRST (HBM-latency loads) ----
    f32x2 pa0, pa1, pb0, pb1;   // rows {2u,2u+1} x cols {c2,c2+1}
    { const float* wp = wrow(0); pa0 = *(const f32x2*)wp; pa1 = *(const f32x2*)(wp + kPCols); }
    { const float* wp = wrow(1); pb0 = *(const f32x2*)wp; pb1 = *(const f32x2*)(wp + kPCols); }

    // bvec -> LDS
    for (int idx = tid; idx < (kITile + 1) * kOTile; idx += 1024) {
        const int p = idx >> 5, c = idx & 31;
        const size_t cb = (p == kITile) ? (size_t)(kIn * kOut) : (size_t)(i0 + p) * kOut;
        bv_lds[idx] = bvec[cb + o0 + c];
    }

    // feats[b][i0+i] -> feats_lds[i][b]
    {
        const int i    = tid & 15;
        const int brow = tid >> 4;      // 0..63
        #pragma unroll
        for (int rep = 0; rep < 4; ++rep) {
            const int b = brow + rep * 64;
            feats_lds[i * kFeatsStride + b] = x[b * kXCols + kNoise + i0 + i];
        }
    }

    // Noise A-fragments (resident, 16 VGPRs). A[m=lane&15][k=q*8+j], k_global=32*s+k.
    bf16x8 afrag[4];
    {
        const float* xr = x + (size_t)(wave * 16 + l16) * kXCols;
        #pragma unroll
        for (int s = 0; s < 4; ++s) {
            const float* p = xr + s * 32 + q * 8;
            f32x4 u0 = *(const f32x4*)(p);
            f32x4 u1 = *(const f32x4*)(p + 4);
            bf16x8 a;
            a[0] = (__bf16)u0[0]; a[1] = (__bf16)u0[1];
            a[2] = (__bf16)u0[2]; a[3] = (__bf16)u0[3];
            a[4] = (__bf16)u1[0]; a[5] = (__bf16)u1[1];
            a[6] = (__bf16)u1[2]; a[7] = (__bf16)u1[3];
            afrag[s] = a;
        }
    }

    float oacc[2][4];   // [nt][r]; b = wave*16+q*4+r, o = o0+nt*16+l16
    #pragma unroll
    for (int nt = 0; nt < 2; ++nt)
        #pragma unroll
        for (int r = 0; r < 4; ++r) oacc[nt][r] = 0.f;

    __syncthreads();   // feats + bvec staged

    // ---- pipelined i-loop: 1 barrier/pass, steady-state vmcnt never drains ----
    for (int ip = 0; ip < nPass; ++ip) {
        // pack pass-ip regs (compiler waits only the oldest pair of loads)
        unsigned int pk0 = pack_bf16x2(pa0[0], pa1[0]);
        unsigned int pk1 = pack_bf16x2(pa0[1], pa1[1]);

        unsigned int* wt = &wtile[ip & 1][0];
        wt[(c2    ) * kWStride + u] = pk0;
        wt[(c2 + 1) * kWStride + u] = pk1;

        pa0 = pb0; pa1 = pb1;
        if (ip + 2 < nPass) {
            const float* wp = wrow(ip + 2);
            pb0 = *(const f32x2*)wp; pb1 = *(const f32x2*)(wp + kPCols);
        }

        wg_barrier_lds();   // tile[ip&1] visible; prior-buffer readers done

        // GEMM: acc[b,col] = noise @ W[:, cbase+o0+col]
        f32x4 acc[2];
        const f32x4 zero = {0.f, 0.f, 0.f, 0.f};
        acc[0] = zero; acc[1] = zero;

        #pragma unroll
        for (int s = 0; s < 4; ++s) {
            #pragma unroll
            for (int nt = 0; nt < 2; ++nt) {
                // B layout [k=q*8+j][col=l16]: 4 consecutive uints = 8 bf16 (k asc)
                u32x4 raw = *(const u32x4*)&wt[(nt * 16 + l16) * kWStride + s * 16 + q * 4];
                bf16x8 bfrag = __builtin_bit_cast(bf16x8, raw);
                acc[nt] = __builtin_amdgcn_mfma_f32_16x16x32_bf16(
                    afrag[s], bfrag, acc[nt], 0, 0, 0);
            }
        }

        // epilogue (fp32): oacc += feats[b,i] * (acc + bvec[c]); bias pass scale=1
        const float bv0 = bv_lds[ip * kOTile + l16];
        const float bv1 = bv_lds[ip * kOTile + 16 + l16];

        if (ip < kITile) {
            // C/D layout: col = lane&15, row = q*4 + reg
            const f32x4 f4 = *(const f32x4*)&feats_lds[ip * kFeatsStride
                                    + wave * 16 + q * 4];
            #pragma unroll
            for (int r = 0; r < 4; ++r) {
                oacc[0][r] += f4[r] * (acc[0][r] + bv0);
                oacc[1][r] += f4[r] * (acc[1][r] + bv1);
            }
        } else {
            #pragma unroll
            for (int r = 0; r < 4; ++r) {
                oacc[0][r] += acc[0][r] + bv0;
                oacc[1][r] += acc[1][r] + bv1;
            }
        }
    }

    // ---- stream partials (no atomics) ----
    float* pp = part + (size_t)blockIdx.y * kBatch * kOut;
    #pragma unroll
    for (int nt = 0; nt < 2; ++nt) {
        const int o = o0 + nt * 16 + l16;
        #pragma unroll
        for (int r = 0; r < 4; ++r) {
            const int b = wave * 16 + q * 4 + r;
            pp[(size_t)b * kOut + o] = oacc[nt][r];
        }
    }
}

// Stage 2: out = sum over 32 slabs (16.8 MB, L2/L3-resident)
__global__ __launch_bounds__(256)
void reduce_kernel(const float* __restrict__ part, float* __restrict__ out)
{
    const size_t idx4 = ((size_t)blockIdx.x * 256 + threadIdx.x) * 4;
    f32x4 acc = *(const f32x4*)(part + idx4);
    #pragma unroll
    for (int s = 1; s < kSplits; ++s)
        acc += *(const f32x4*)(part + (size_t)s * kBatch * kOut + idx4);
    *(f32x4*)(out + idx4) = acc;
}

extern "C" void kernel_launch(void* const* d_in, const int* in_sizes, int n_in,
                              void* d_out, int out_size, void* d_ws, size_t ws_size,
                              hipStream_t stream) {
    const float* x  = (const float*)d_in[0];
    const float* W  = (const float*)d_in[1];
    const float* bv = (const float*)d_in[2];
    float* out  = (float*)d_out;
    float* part = (float*)d_ws;   // 32 * 256 * 512 * 4 B = 16.8 MB

    dim3 grid(kOut / kOTile, kSplits);  // (16, 32) = 512 WGs of 1024 threads
    hyper_gemm_kernel<<<grid, 1024, 0, stream>>>(x, W, bv, part);

    const int n4 = kBatch * kOut / 4;   // 32768 f32x4 outputs
    reduce_kernel<<<n4 / 256, 256, 0, stream>>>(part, out);
}